// Round 8
// baseline (484.177 us; speedup 1.0000x reference)
//
#include <hip/hip_runtime.h>
#include <hip/hip_bf16.h>

typedef __attribute__((ext_vector_type(4)))  float f32x4;
typedef __attribute__((ext_vector_type(16))) float f32x16;
typedef __attribute__((ext_vector_type(8)))  short short8;

#define XROWS 8195            // 3 guard rows + 8192
#define XBATCH (XROWS * 1024) // elems per padded batch

__device__ __forceinline__ short f2bf(float f) {
    union { __hip_bfloat16 h; short s; } u;
    u.h = __float2bfloat16(f);
    return u.s;
}

__device__ __forceinline__ void async16(const void* g, void* l) {
    __builtin_amdgcn_global_load_lds(
        (const __attribute__((address_space(1))) unsigned int*)g,
        (__attribute__((address_space(3))) unsigned int*)l, 16, 0, 0);
}

// ---------------------------------------------------------------------------
// Prepass 1: x fp32 [4][8192][1024] -> Xbf bf16 [4][3+8192][1024], guard=0
// ---------------------------------------------------------------------------
__global__ void x_to_bf16(const float* __restrict__ x,
                          __hip_bfloat16* __restrict__ Xbf) {
    size_t idx = (size_t)blockIdx.x * blockDim.x + threadIdx.x;
    if (idx < 1536) {  // zero 4*3*1024 guard elems
        int b = (int)(idx / 384);
        int r = (int)(idx % 384);
        *reinterpret_cast<short8*>(&Xbf[(size_t)b * XBATCH + r * 8]) =
            (short8){0, 0, 0, 0, 0, 0, 0, 0};
    }
    size_t stride = (size_t)gridDim.x * blockDim.x;
    const size_t nvec = (size_t)4 * 8192 * 1024 / 8;
    for (size_t v = idx; v < nvec; v += stride) {
        size_t e = v * 8;
        int b = (int)(e >> 23);
        size_t rem = e & ((1u << 23) - 1);
        f32x4 lo = *reinterpret_cast<const f32x4*>(x + e);
        f32x4 hi = *reinterpret_cast<const f32x4*>(x + e + 4);
        short8 pk;
        pk[0] = f2bf(lo[0]); pk[1] = f2bf(lo[1]); pk[2] = f2bf(lo[2]); pk[3] = f2bf(lo[3]);
        pk[4] = f2bf(hi[0]); pk[5] = f2bf(hi[1]); pk[6] = f2bf(hi[2]); pk[7] = f2bf(hi[3]);
        *reinterpret_cast<short8*>(&Xbf[(size_t)b * XBATCH + 3 * 1024 + rem]) = pk;
    }
}

// ---------------------------------------------------------------------------
// Prepass 2: kernels [4096][1024] fp32 -> Kt [1024][4096] bf16
// ---------------------------------------------------------------------------
__global__ void kconv_transpose(const float* __restrict__ kern,
                                __hip_bfloat16* __restrict__ Kt) {
    __shared__ float tile[32][33];
    int k0 = blockIdx.x << 5;
    int f0 = blockIdx.y << 5;
    int tx = threadIdx.x & 31;
    int ty = threadIdx.x >> 5;
#pragma unroll
    for (int q = 0; q < 4; q++)
        tile[ty + q * 8][tx] = kern[(size_t)(k0 + ty + q * 8) * 1024 + f0 + tx];
    __syncthreads();
#pragma unroll
    for (int q = 0; q < 4; q++)
        Kt[((size_t)(f0 + ty + q * 8) << 12) + k0 + tx] =
            __float2bfloat16(tile[tx][ty + q * 8]);
}

// ---------------------------------------------------------------------------
// Main GEMM — flatmm-style, LDS-traffic-minimized:
//   BM=BN=256, 8 waves (2M x 4N), wave tile 128x64, MFMA 32x32x16 bf16.
//   A: LDS, FRAGMENT-MAJOR layout (chunk order = (kstep, m-frag, lane)) ->
//      ds_read_b128 at uniform+lane*16, conflict-free, no swizzle; DMA dest
//      linear (thread t stages m-frag wid, lane chunk, all 4 ksteps).
//      Double-buffered 2 x 32KB = 64 KiB total LDS.
//   B: NEVER in LDS — per-wave global->reg loads (8 dwordx4 / K-tile),
//      double-buffered in registers, prefetched one full tile ahead
//      (L1/L2-hot; per-inst gather 32 rows x 32B, lines fully consumed).
//   Sync: ONE vmcnt(0)+s_barrier per K-tile; issue->wait distance = full
//      tile (~2000 cyc) so the drain is free (R5-proven wait pattern).
//   LDS traffic/K-tile/CU: 128KB read + 32KB write (was 256KB) -> ~69% pipe.
// ---------------------------------------------------------------------------
__global__ void __launch_bounds__(512, 2)
altconv_gemm8(const __hip_bfloat16* __restrict__ Xbf,  // [4][8195][1024]
              const __hip_bfloat16* __restrict__ Kt,   // [1024][4096]
              const float* __restrict__ biases,        // [4][1024]
              float* __restrict__ out) {               // [32768][1024]
    __shared__ alignas(16) __hip_bfloat16 LS[2 * 16384];  // 64 KiB, A only

    // bijective XCD swizzle (512 % 8 == 0); nt fastest within an XCD chunk
    int bid  = blockIdx.x;
    int tid2 = (bid & 7) * 64 + (bid >> 3);
    int mt = tid2 >> 2;           // 0..127
    int nt = tid2 & 3;            // 0..3
    int bm0   = mt << 8;
    int batch = bm0 >> 13;
    int srow0 = bm0 & 8191;
    int bn0   = nt << 8;
    const __hip_bfloat16* xb =
        Xbf + (size_t)batch * XBATCH + (size_t)(srow0 + 3) * 1024;

    int t    = threadIdx.x;
    int lane = t & 63;
    int wid  = t >> 6;            // 0..7
    int wr = wid >> 2, wc = wid & 3;
    int l31 = lane & 31, lh = lane >> 5;

    // A staging: thread stages m-frag == wid, lane chunk == lane, ksteps 0..3
    int asrc = (wid * 32 + l31) * 1024 + lh * 8;  // + kstep*16 + tile base
    // B reg-load base: row = bn0 + wc*64 + (n*32) + l31, k = T*64 + ks*16 + lh*8
    const __hip_bfloat16* bbase =
        Kt + ((size_t)(bn0 + wc * 64 + l31) << 12) + lh * 8;

    f32x16 acc[4][2];
#pragma unroll
    for (int m = 0; m < 4; m++)
#pragma unroll
        for (int n = 0; n < 2; n++)
#pragma unroll
            for (int r = 0; r < 16; r++) acc[m][n][r] = 0.f;

    short8 Ba[2][4], Bb[2][4];   // [n][ks], double-buffered in regs

#define STAGE_A(TN) do {                                                      \
        int tap_ = (TN) >> 4;                                                 \
        int c0_  = ((TN) & 15) << 6;                                          \
        const __hip_bfloat16* aS_ = xb - tap_ * 1024 + c0_ + asrc;            \
        int dE_ = ((TN) & 1) << 14;                                           \
        _Pragma("unroll")                                                     \
        for (int i = 0; i < 4; i++)                                           \
            async16(aS_ + i * 16, &LS[dE_ + (i * 512 + t) * 8]);              \
    } while (0)

#define LOADB(TN, DST) do {                                                   \
        const __hip_bfloat16* b0_ = bbase + (TN) * 64;                        \
        _Pragma("unroll")                                                     \
        for (int n = 0; n < 2; n++)                                           \
            _Pragma("unroll")                                                 \
            for (int ks = 0; ks < 4; ks++)                                    \
                DST[n][ks] = *reinterpret_cast<const short8*>(                \
                    b0_ + n * 131072 + ks * 16);                              \
    } while (0)

#define TILE(T, BC, BNX) do {                                                 \
        int Tn_ = ((T) + 1) & 63;                                             \
        STAGE_A(Tn_);                                                         \
        LOADB(Tn_, BNX);                                                      \
        int bufE_ = ((T) & 1) << 14;                                          \
        _Pragma("unroll")                                                     \
        for (int ks = 0; ks < 4; ks++) {                                      \
            short8 af[4];                                                     \
            _Pragma("unroll")                                                 \
            for (int m = 0; m < 4; m++)                                       \
                af[m] = *reinterpret_cast<const short8*>(                     \
                    &LS[bufE_ + ((ks * 8 + wr * 4 + m) * 512 + lane * 8)]);   \
            __builtin_amdgcn_s_setprio(1);                                    \
            _Pragma("unroll")                                                 \
            for (int m = 0; m < 4; m++)                                       \
                _Pragma("unroll")                                             \
                for (int n = 0; n < 2; n++)                                   \
                    acc[m][n] = __builtin_amdgcn_mfma_f32_32x32x16_bf16(      \
                        af[m], BC[n][ks], acc[m][n], 0, 0, 0);                \
            __builtin_amdgcn_s_setprio(0);                                    \
        }                                                                     \
        asm volatile("s_waitcnt vmcnt(0)" ::: "memory");                      \
        __builtin_amdgcn_s_barrier();                                         \
        asm volatile("" ::: "memory");                                        \
    } while (0)

    // prologue: stage A[0], load B[0]; wait; barrier
    STAGE_A(0);
    LOADB(0, Ba);
    asm volatile("s_waitcnt vmcnt(0)" ::: "memory");
    __builtin_amdgcn_s_barrier();
    asm volatile("" ::: "memory");

    for (int T = 0; T < 64; T += 2) {
        TILE(T, Ba, Bb);
        TILE(T + 1, Bb, Ba);
    }

    // epilogue: 32x32 C/D layout col=lane&31, row=(r&3)+8*(r>>2)+4*(lane>>5)
#pragma unroll
    for (int n = 0; n < 2; n++) {
        int gc = bn0 + wc * 64 + n * 32 + l31;
        float bsum = biases[gc] + biases[1024 + gc] + biases[2048 + gc] + biases[3072 + gc];
#pragma unroll
        for (int m = 0; m < 4; m++) {
            int rowb = bm0 + wr * 128 + m * 32 + 4 * lh;
#pragma unroll
            for (int r = 0; r < 16; r++) {
                int row = rowb + (r & 3) + 8 * (r >> 2);
                out[(size_t)row * 1024 + gc] = acc[m][n][r] + bsum;
            }
        }
    }
#undef STAGE_A
#undef LOADB
#undef TILE
}

// ---------------------------------------------------------------------------
// Fallback: plain fp32 (no workspace needed), correct but slow
// ---------------------------------------------------------------------------
__global__ void fallback_conv(const float* __restrict__ x, const float* __restrict__ kern,
                              const float* __restrict__ biases, float* __restrict__ out) {
    __shared__ float xs[1024];
    int row = blockIdx.x;
    int f = (blockIdx.y << 8) + threadIdx.x;
    int batch = row >> 13, s = row & 8191;
    const float* xb = x + (((size_t)batch << 13) << 10);
    float acc = 0.f;
    for (int tap = 0; tap < 4; tap++) {
        int ss = s - tap;
        __syncthreads();
        for (int i = threadIdx.x; i < 1024; i += 256)
            xs[i] = (ss >= 0) ? xb[((size_t)ss << 10) + i] : 0.f;
        __syncthreads();
        const float* kp = kern + ((size_t)tap << 20) + f;
        float a = 0.f;
        for (int d = 0; d < 1024; d++) a += xs[d] * kp[(size_t)d << 10];
        acc += a + biases[(tap << 10) + f];
    }
    out[((size_t)row << 10) + f] = acc;
}

extern "C" void kernel_launch(void* const* d_in, const int* in_sizes, int n_in,
                              void* d_out, int out_size, void* d_ws, size_t ws_size,
                              hipStream_t stream) {
    const float* x      = (const float*)d_in[0];
    const float* kern   = (const float*)d_in[1];
    const float* biases = (const float*)d_in[2];
    float* out = (float*)d_out;

    const size_t xbf_bytes = (size_t)4 * XBATCH * sizeof(__hip_bfloat16); // 67.1 MB
    const size_t kt_bytes  = (size_t)4096 * 1024 * sizeof(__hip_bfloat16); // 8.4 MB

    if (ws_size >= xbf_bytes + kt_bytes) {
        __hip_bfloat16* Xbf = (__hip_bfloat16*)d_ws;
        __hip_bfloat16* Kt  = (__hip_bfloat16*)((char*)d_ws + xbf_bytes);
        x_to_bf16<<<2048, 256, 0, stream>>>(x, Xbf);
        kconv_transpose<<<dim3(128, 32), 256, 0, stream>>>(kern, Kt);
        altconv_gemm8<<<512, 512, 0, stream>>>(Xbf, Kt, biases, out);
    } else {
        fallback_conv<<<dim3(32768, 4), 256, 0, stream>>>(x, kern, biases, out);
    }
}

// Round 11
// 336.584 us; speedup vs baseline: 1.4385x; 1.4385x over previous
//
#include <hip/hip_runtime.h>
#include <hip/hip_bf16.h>

typedef __attribute__((ext_vector_type(4)))  float f32x4;
typedef __attribute__((ext_vector_type(16))) float f32x16;
typedef __attribute__((ext_vector_type(8)))  short short8;

#define XROWS 8195            // 3 guard rows + 8192
#define XBATCH (XROWS * 1024) // elems per padded batch

__device__ __forceinline__ short f2bf(float f) {
    union { __hip_bfloat16 h; short s; } u;
    u.h = __float2bfloat16(f);
    return u.s;
}

__device__ __forceinline__ void async16(const void* g, void* l) {
    __builtin_amdgcn_global_load_lds(
        (const __attribute__((address_space(1))) unsigned int*)g,
        (__attribute__((address_space(3))) unsigned int*)l, 16, 0, 0);
}

// ---------------------------------------------------------------------------
// Prepass 1: x fp32 [4][8192][1024] -> Xbf bf16 [4][3+8192][1024], guard=0
// ---------------------------------------------------------------------------
__global__ void x_to_bf16(const float* __restrict__ x,
                          __hip_bfloat16* __restrict__ Xbf) {
    size_t idx = (size_t)blockIdx.x * blockDim.x + threadIdx.x;
    if (idx < 1536) {  // zero 4*3*1024 guard elems
        int b = (int)(idx / 384);
        int r = (int)(idx % 384);
        *reinterpret_cast<short8*>(&Xbf[(size_t)b * XBATCH + r * 8]) =
            (short8){0, 0, 0, 0, 0, 0, 0, 0};
    }
    size_t stride = (size_t)gridDim.x * blockDim.x;
    const size_t nvec = (size_t)4 * 8192 * 1024 / 8;
    for (size_t v = idx; v < nvec; v += stride) {
        size_t e = v * 8;
        int b = (int)(e >> 23);
        size_t rem = e & ((1u << 23) - 1);
        f32x4 lo = *reinterpret_cast<const f32x4*>(x + e);
        f32x4 hi = *reinterpret_cast<const f32x4*>(x + e + 4);
        short8 pk;
        pk[0] = f2bf(lo[0]); pk[1] = f2bf(lo[1]); pk[2] = f2bf(lo[2]); pk[3] = f2bf(lo[3]);
        pk[4] = f2bf(hi[0]); pk[5] = f2bf(hi[1]); pk[6] = f2bf(hi[2]); pk[7] = f2bf(hi[3]);
        *reinterpret_cast<short8*>(&Xbf[(size_t)b * XBATCH + 3 * 1024 + rem]) = pk;
    }
}

// ---------------------------------------------------------------------------
// Prepass 2: kernels [4096][1024] fp32 -> Bf fragment-major bf16.
//   Bf elem offset = T*65536 + nb*2048 + ks*512 + lane*8 + e
//   value = B(k = T*64 + ks*16 + (lane>>5)*8 + e, f = nb*32 + (lane&31))
//   T in [0,64), nb in [0,32), ks in [0,4), lane in [0,64), e in [0,8).
//   Grid 2048x256 = 524288 fragments = full 4096x1024 B. In-bounds:
//   max elem = 63*65536+31*2048+3*512+63*8+7 = 4,194,303.
// ---------------------------------------------------------------------------
__global__ void kconv_frag(const float* __restrict__ kern,
                           __hip_bfloat16* __restrict__ Bf) {
    int id   = blockIdx.x * 256 + threadIdx.x;   // 0..524287
    int lane = id & 63;
    int ks   = (id >> 6) & 3;
    int nb   = (id >> 8) & 31;
    int T    = id >> 13;
    int f    = nb * 32 + (lane & 31);
    int kb   = T * 64 + ks * 16 + ((lane >> 5) << 3);
    short8 pk;
#pragma unroll
    for (int e = 0; e < 8; e++)
        pk[e] = f2bf(kern[(size_t)(kb + e) * 1024 + f]);
    *reinterpret_cast<short8*>(&Bf[(size_t)id * 8]) = pk;
}

// ---------------------------------------------------------------------------
// Main GEMM — R8's proven skeleton + its two diagnosed fixes:
//   BM=BN=256, 8 waves (2M x 4N), wave tile 128x64, MFMA 32x32x16.
//   A: LDS fragment-major (R8-proven, 0 conflicts), 2x32KB dbuf, linear DMA.
//   B: plain C++ loads from fragment-major Bf (1KB contiguous/inst,
//      COALESCED — fixes R8's 8KB-stride gather), reg double-buffered,
//      prefetched 1 tile ahead; compiler auto-inserts the counted wait
//      before the MFMA that consumes them (loads-to-use, not drain).
//   End-of-tile: asm vmcnt(8) + s_barrier — drains only A-DMA(T+1)
//      (fixes R8's vmcnt(0) full drain); B(T+1) stays in flight.
// ---------------------------------------------------------------------------
__global__ void __launch_bounds__(512, 2)
altconv_gemm9(const __hip_bfloat16* __restrict__ Xbf,  // [4][8195][1024]
              const __hip_bfloat16* __restrict__ Bf,   // fragment-major B
              const float* __restrict__ biases,        // [4][1024]
              float* __restrict__ out) {               // [32768][1024]
    __shared__ alignas(16) __hip_bfloat16 LS[2 * 16384];  // 64 KiB, A only

    // bijective XCD swizzle (512 % 8 == 0); nt fastest within an XCD chunk
    int bid  = blockIdx.x;
    int tid2 = (bid & 7) * 64 + (bid >> 3);
    int mt = tid2 >> 2;           // 0..127
    int nt = tid2 & 3;            // 0..3
    int bm0   = mt << 8;
    int batch = bm0 >> 13;
    int srow0 = bm0 & 8191;
    int bn0   = nt << 8;
    const __hip_bfloat16* xb =
        Xbf + (size_t)batch * XBATCH + (size_t)(srow0 + 3) * 1024;

    int t    = threadIdx.x;
    int lane = t & 63;
    int wid  = t >> 6;            // 0..7
    int wr = wid >> 2, wc = wid & 3;
    int l31 = lane & 31, lh = lane >> 5;

    // A staging: thread stages row wid*32+l31, k chunks lh*8 + i*16
    int asrc = (wid * 32 + l31) * 1024 + lh * 8;
    // B wave base: nb = bn0/32 + wc*2 + n -> offset nb*2048 + lane*8
    const __hip_bfloat16* bfw =
        Bf + (size_t)((bn0 >> 5) + wc * 2) * 2048 + (size_t)lane * 8;

    f32x16 acc[4][2];
#pragma unroll
    for (int m = 0; m < 4; m++)
#pragma unroll
        for (int n = 0; n < 2; n++)
#pragma unroll
            for (int r = 0; r < 16; r++) acc[m][n][r] = 0.f;

    short8 Ba[2][4], Bb[2][4];   // [n][ks] reg double-buffer

#define STAGE_A(TN) do {                                                      \
        int tap_ = (TN) >> 4;                                                 \
        int c0_  = ((TN) & 15) << 6;                                          \
        const __hip_bfloat16* aS_ = xb - tap_ * 1024 + c0_ + asrc;            \
        int dE_ = ((TN) & 1) << 14;                                           \
        _Pragma("unroll")                                                     \
        for (int i = 0; i < 4; i++)                                           \
            async16(aS_ + i * 16, &LS[dE_ + (i * 512 + t) * 8]);              \
    } while (0)

#define LOADB(TN, DST) do {                                                   \
        const __hip_bfloat16* b0_ = bfw + (size_t)(TN) * 65536;               \
        _Pragma("unroll")                                                     \
        for (int n = 0; n < 2; n++)                                           \
            _Pragma("unroll")                                                 \
            for (int ks = 0; ks < 4; ks++)                                    \
                DST[n][ks] = *reinterpret_cast<const short8*>(                \
                    b0_ + n * 2048 + ks * 512);                               \
    } while (0)

#define TILE(T, BC, BNX) do {                                                 \
        int Tn_ = ((T) + 1) & 63;                                             \
        STAGE_A(Tn_);                                                         \
        asm volatile("" ::: "memory");      /* pin A-DMA before B issue */    \
        LOADB(Tn_, BNX);                                                      \
        int bufE_ = ((T) & 1) << 14;                                          \
        _Pragma("unroll")                                                     \
        for (int ks = 0; ks < 4; ks++) {                                      \
            short8 af[4];                                                     \
            _Pragma("unroll")                                                 \
            for (int m = 0; m < 4; m++)                                       \
                af[m] = *reinterpret_cast<const short8*>(                     \
                    &LS[bufE_ + ((ks * 8 + wr * 4 + m) * 512 + lane * 8)]);   \
            __builtin_amdgcn_s_setprio(1);                                    \
            _Pragma("unroll")                                                 \
            for (int m = 0; m < 4; m++)                                       \
                _Pragma("unroll")                                             \
                for (int n = 0; n < 2; n++)                                   \
                    acc[m][n] = __builtin_amdgcn_mfma_f32_32x32x16_bf16(      \
                        af[m], BC[n][ks], acc[m][n], 0, 0, 0);                \
            __builtin_amdgcn_s_setprio(0);                                    \
        }                                                                     \
        asm volatile("s_waitcnt vmcnt(8)" ::: "memory");                      \
        __builtin_amdgcn_s_barrier();                                         \
        asm volatile("" ::: "memory");                                        \
    } while (0)

    // prologue: A(0) then B(0); vmcnt(8) drains A(0) (oldest 4 of 12)
    STAGE_A(0);
    asm volatile("" ::: "memory");
    LOADB(0, Ba);
    asm volatile("s_waitcnt vmcnt(8)" ::: "memory");
    __builtin_amdgcn_s_barrier();
    asm volatile("" ::: "memory");

    for (int T = 0; T < 64; T += 2) {
        TILE(T, Ba, Bb);
        TILE(T + 1, Bb, Ba);
    }

    // epilogue: 32x32 C/D layout col=lane&31, row=(r&3)+8*(r>>2)+4*(lane>>5)
#pragma unroll
    for (int n = 0; n < 2; n++) {
        int gc = bn0 + wc * 64 + n * 32 + l31;
        float bsum = biases[gc] + biases[1024 + gc] + biases[2048 + gc] + biases[3072 + gc];
#pragma unroll
        for (int m = 0; m < 4; m++) {
            int rowb = bm0 + wr * 128 + m * 32 + 4 * lh;
#pragma unroll
            for (int r = 0; r < 16; r++) {
                int row = rowb + (r & 3) + 8 * (r >> 2);
                out[(size_t)row * 1024 + gc] = acc[m][n][r] + bsum;
            }
        }
    }
#undef STAGE_A
#undef LOADB
#undef TILE
}

// ---------------------------------------------------------------------------
// Fallback: plain fp32 (no workspace needed), correct but slow
// ---------------------------------------------------------------------------
__global__ void fallback_conv(const float* __restrict__ x, const float* __restrict__ kern,
                              const float* __restrict__ biases, float* __restrict__ out) {
    __shared__ float xs[1024];
    int row = blockIdx.x;
    int f = (blockIdx.y << 8) + threadIdx.x;
    int batch = row >> 13, s = row & 8191;
    const float* xb = x + (((size_t)batch << 13) << 10);
    float acc = 0.f;
    for (int tap = 0; tap < 4; tap++) {
        int ss = s - tap;
        __syncthreads();
        for (int i = threadIdx.x; i < 1024; i += 256)
            xs[i] = (ss >= 0) ? xb[((size_t)ss << 10) + i] : 0.f;
        __syncthreads();
        const float* kp = kern + ((size_t)tap << 20) + f;
        float a = 0.f;
        for (int d = 0; d < 1024; d++) a += xs[d] * kp[(size_t)d << 10];
        acc += a + biases[(tap << 10) + f];
    }
    out[((size_t)row << 10) + f] = acc;
}

extern "C" void kernel_launch(void* const* d_in, const int* in_sizes, int n_in,
                              void* d_out, int out_size, void* d_ws, size_t ws_size,
                              hipStream_t stream) {
    const float* x      = (const float*)d_in[0];
    const float* kern   = (const float*)d_in[1];
    const float* biases = (const float*)d_in[2];
    float* out = (float*)d_out;

    const size_t xbf_bytes = (size_t)4 * XBATCH * sizeof(__hip_bfloat16); // 67.1 MB
    const size_t bf_bytes  = (size_t)4096 * 1024 * sizeof(__hip_bfloat16); // 8.4 MB

    if (ws_size >= xbf_bytes + bf_bytes) {
        __hip_bfloat16* Xbf = (__hip_bfloat16*)d_ws;
        __hip_bfloat16* Bfr = (__hip_bfloat16*)((char*)d_ws + xbf_bytes);
        x_to_bf16<<<2048, 256, 0, stream>>>(x, Xbf);
        kconv_frag<<<2048, 256, 0, stream>>>(kern, Bfr);
        altconv_gemm9<<<512, 512, 0, stream>>>(Xbf, Bfr, biases, out);
    } else {
        fallback_conv<<<dim3(32768, 4), 256, 0, stream>>>(x, kern, biases, out);
    }
}

// Round 12
// 328.929 us; speedup vs baseline: 1.4720x; 1.0233x over previous
//
#include <hip/hip_runtime.h>
#include <hip/hip_bf16.h>

typedef __attribute__((ext_vector_type(4)))  float f32x4;
typedef __attribute__((ext_vector_type(16))) float f32x16;
typedef __attribute__((ext_vector_type(8)))  short short8;

#define XROWS 8195            // 3 guard rows + 8192
#define XBATCH (XROWS * 1024) // elems per padded batch

__device__ __forceinline__ short f2bf(float f) {
    union { __hip_bfloat16 h; short s; } u;
    u.h = __float2bfloat16(f);
    return u.s;
}

__device__ __forceinline__ void async16(const void* g, void* l) {
    __builtin_amdgcn_global_load_lds(
        (const __attribute__((address_space(1))) unsigned int*)g,
        (__attribute__((address_space(3))) unsigned int*)l, 16, 0, 0);
}

// ---------------------------------------------------------------------------
// Prepass 1: x fp32 [4][8192][1024] -> Xbf bf16 [4][3+8192][1024], guard=0
// ---------------------------------------------------------------------------
__global__ void x_to_bf16(const float* __restrict__ x,
                          __hip_bfloat16* __restrict__ Xbf) {
    size_t idx = (size_t)blockIdx.x * blockDim.x + threadIdx.x;
    if (idx < 1536) {  // zero 4*3*1024 guard elems
        int b = (int)(idx / 384);
        int r = (int)(idx % 384);
        *reinterpret_cast<short8*>(&Xbf[(size_t)b * XBATCH + r * 8]) =
            (short8){0, 0, 0, 0, 0, 0, 0, 0};
    }
    size_t stride = (size_t)gridDim.x * blockDim.x;
    const size_t nvec = (size_t)4 * 8192 * 1024 / 8;
    for (size_t v = idx; v < nvec; v += stride) {
        size_t e = v * 8;
        int b = (int)(e >> 23);
        size_t rem = e & ((1u << 23) - 1);
        f32x4 lo = *reinterpret_cast<const f32x4*>(x + e);
        f32x4 hi = *reinterpret_cast<const f32x4*>(x + e + 4);
        short8 pk;
        pk[0] = f2bf(lo[0]); pk[1] = f2bf(lo[1]); pk[2] = f2bf(lo[2]); pk[3] = f2bf(lo[3]);
        pk[4] = f2bf(hi[0]); pk[5] = f2bf(hi[1]); pk[6] = f2bf(hi[2]); pk[7] = f2bf(hi[3]);
        *reinterpret_cast<short8*>(&Xbf[(size_t)b * XBATCH + 3 * 1024 + rem]) = pk;
    }
}

// ---------------------------------------------------------------------------
// Prepass 2: kernels [4096][1024] fp32 -> Bf fragment-major bf16.
//   Bf elem offset = T*65536 + nb*2048 + ks*512 + lane*8 + e
//   value = B(k = T*64 + ks*16 + (lane>>5)*8 + e, f = nb*32 + (lane&31))
// ---------------------------------------------------------------------------
__global__ void kconv_frag(const float* __restrict__ kern,
                           __hip_bfloat16* __restrict__ Bf) {
    int id   = blockIdx.x * 256 + threadIdx.x;   // 0..524287
    int lane = id & 63;
    int ks   = (id >> 6) & 3;
    int nb   = (id >> 8) & 31;
    int T    = id >> 13;
    int f    = nb * 32 + (lane & 31);
    int kb   = T * 64 + ks * 16 + ((lane >> 5) << 3);
    short8 pk;
#pragma unroll
    for (int e = 0; e < 8; e++)
        pk[e] = f2bf(kern[(size_t)(kb + e) * 1024 + f]);
    *reinterpret_cast<short8*>(&Bf[(size_t)id * 8]) = pk;
}

// ---------------------------------------------------------------------------
// Main GEMM — flatmm (R11 layouts, proven) + software-pipelined tile body:
//   BM=BN=256, 8 waves (2M x 4N), wave tile 128x64, MFMA 32x32x16.
//   A: LDS fragment-major, 2x32KB dbuf, linear DMA (0 conflicts).
//   B: coalesced fragment-major Bf -> regs, dbuf, prefetch 1 tile ahead.
//   NEW: ks-ping-pong A frags (afA/afB) — ds_reads for ks+1 overlap
//   MFMA(ks); B(T+1) loads split in two 4-load groups between phases;
//   A-DMA issued first (oldest) so tile-end vmcnt(8) drains only A-DMA.
//   Compiler emits counted lgkmcnt for af prefetch and counted vmcnt(8)
//   for B(T) consumption (8 younger ops in flight). Never a full drain.
// ---------------------------------------------------------------------------
__global__ void __launch_bounds__(512, 2)
altconv_gemm10(const __hip_bfloat16* __restrict__ Xbf,  // [4][8195][1024]
               const __hip_bfloat16* __restrict__ Bf,   // fragment-major B
               const float* __restrict__ biases,        // [4][1024]
               float* __restrict__ out) {               // [32768][1024]
    __shared__ alignas(16) __hip_bfloat16 LS[2 * 16384];  // 64 KiB, A only

    // bijective XCD swizzle (512 % 8 == 0); nt fastest within an XCD chunk
    int bid  = blockIdx.x;
    int tid2 = (bid & 7) * 64 + (bid >> 3);
    int mt = tid2 >> 2;           // 0..127
    int nt = tid2 & 3;            // 0..3
    int bm0   = mt << 8;
    int batch = bm0 >> 13;
    int srow0 = bm0 & 8191;
    int bn0   = nt << 8;
    const __hip_bfloat16* xb =
        Xbf + (size_t)batch * XBATCH + (size_t)(srow0 + 3) * 1024;

    int t    = threadIdx.x;
    int lane = t & 63;
    int wid  = t >> 6;            // 0..7
    int wr = wid >> 2, wc = wid & 3;
    int l31 = lane & 31, lh = lane >> 5;

    // A staging: thread stages row wid*32+l31, k chunks lh*8 + i*16
    int asrc = (wid * 32 + l31) * 1024 + lh * 8;
    // A-fragment read bases (elem): chunk (ks*8 + wr*4 + m)*512 + lane*8
    int aRdB[4];
#pragma unroll
    for (int m = 0; m < 4; m++) aRdB[m] = (wr * 4 + m) * 512 + lane * 8;
    // B wave base: nb = bn0/32 + wc*2 + n -> offset nb*2048 + lane*8
    const __hip_bfloat16* bfw =
        Bf + (size_t)((bn0 >> 5) + wc * 2) * 2048 + (size_t)lane * 8;

    f32x16 acc[4][2];
#pragma unroll
    for (int m = 0; m < 4; m++)
#pragma unroll
        for (int n = 0; n < 2; n++)
#pragma unroll
            for (int r = 0; r < 16; r++) acc[m][n][r] = 0.f;

    short8 Ba[2][4], Bb[2][4];   // [n][ks] reg double-buffer

#define STAGE_A(TN) do {                                                      \
        int tap_ = (TN) >> 4;                                                 \
        int c0_  = ((TN) & 15) << 6;                                          \
        const __hip_bfloat16* aS_ = xb - tap_ * 1024 + c0_ + asrc;            \
        int dE_ = ((TN) & 1) << 14;                                           \
        _Pragma("unroll")                                                     \
        for (int i = 0; i < 4; i++)                                           \
            async16(aS_ + i * 16, &LS[dE_ + (i * 512 + t) * 8]);              \
    } while (0)

#define LOADB(TN, DST) do {                                                   \
        const __hip_bfloat16* b0_ = bfw + (size_t)(TN) * 65536;               \
        _Pragma("unroll")                                                     \
        for (int n = 0; n < 2; n++)                                           \
            _Pragma("unroll")                                                 \
            for (int ks = 0; ks < 4; ks++)                                    \
                DST[n][ks] = *reinterpret_cast<const short8*>(                \
                    b0_ + n * 2048 + ks * 512);                               \
    } while (0)

#define RD_AF(DST, KS, BUF) do {                                              \
        _Pragma("unroll")                                                     \
        for (int m = 0; m < 4; m++)                                           \
            DST[m] = *reinterpret_cast<const short8*>(                        \
                &LS[(BUF) + (KS) * 4096 + aRdB[m]]);                          \
    } while (0)

#define MFMA8(AF, BC, KS) do {                                                \
        __builtin_amdgcn_s_setprio(1);                                        \
        _Pragma("unroll")                                                     \
        for (int m = 0; m < 4; m++)                                           \
            _Pragma("unroll")                                                 \
            for (int n = 0; n < 2; n++)                                       \
                acc[m][n] = __builtin_amdgcn_mfma_f32_32x32x16_bf16(          \
                    AF[m], BC[n][KS], acc[m][n], 0, 0, 0);                    \
        __builtin_amdgcn_s_setprio(0);                                        \
    } while (0)

#define TILE(T, BC, BNX) do {                                                 \
        int Tn_   = ((T) + 1) & 63;                                           \
        int bufE_ = ((T) & 1) << 14;                                          \
        short8 afA[4], afB[4];                                                \
        RD_AF(afA, 0, bufE_);               /* ks0 frags */                   \
        STAGE_A(Tn_);                        /* A-DMA first (oldest) */       \
        asm volatile("" ::: "memory");                                        \
        RD_AF(afB, 1, bufE_);               /* ks1 prefetch */                \
        {   const __hip_bfloat16* b0_ = bfw + (size_t)Tn_ * 65536;            \
            _Pragma("unroll")                                                 \
            for (int ks = 0; ks < 4; ks++)                                    \
                BNX[0][ks] = *reinterpret_cast<const short8*>(b0_ + ks * 512);\
        }                                                                     \
        MFMA8(afA, BC, 0);                                                    \
        RD_AF(afA, 2, bufE_);               /* ks2 prefetch */                \
        {   const __hip_bfloat16* b0_ = bfw + (size_t)Tn_ * 65536 + 2048;     \
            _Pragma("unroll")                                                 \
            for (int ks = 0; ks < 4; ks++)                                    \
                BNX[1][ks] = *reinterpret_cast<const short8*>(b0_ + ks * 512);\
        }                                                                     \
        MFMA8(afB, BC, 1);                                                    \
        RD_AF(afB, 3, bufE_);               /* ks3 prefetch */                \
        MFMA8(afA, BC, 2);                                                    \
        MFMA8(afB, BC, 3);                                                    \
        asm volatile("s_waitcnt vmcnt(8)" ::: "memory");  /* drain A-DMA */   \
        __builtin_amdgcn_s_barrier();                                         \
        asm volatile("" ::: "memory");                                        \
    } while (0)

    // prologue: A(0) then B(0); vmcnt(8) drains A(0) (oldest 4 of 12)
    STAGE_A(0);
    asm volatile("" ::: "memory");
    LOADB(0, Ba);
    asm volatile("s_waitcnt vmcnt(8)" ::: "memory");
    __builtin_amdgcn_s_barrier();
    asm volatile("" ::: "memory");

    for (int T = 0; T < 64; T += 2) {
        TILE(T, Ba, Bb);
        TILE(T + 1, Bb, Ba);
    }

    // epilogue: 32x32 C/D layout col=lane&31, row=(r&3)+8*(r>>2)+4*(lane>>5)
#pragma unroll
    for (int n = 0; n < 2; n++) {
        int gc = bn0 + wc * 64 + n * 32 + l31;
        float bsum = biases[gc] + biases[1024 + gc] + biases[2048 + gc] + biases[3072 + gc];
#pragma unroll
        for (int m = 0; m < 4; m++) {
            int rowb = bm0 + wr * 128 + m * 32 + 4 * lh;
#pragma unroll
            for (int r = 0; r < 16; r++) {
                int row = rowb + (r & 3) + 8 * (r >> 2);
                out[(size_t)row * 1024 + gc] = acc[m][n][r] + bsum;
            }
        }
    }
#undef STAGE_A
#undef LOADB
#undef RD_AF
#undef MFMA8
#undef TILE
}

// ---------------------------------------------------------------------------
// Fallback: plain fp32 (no workspace needed), correct but slow
// ---------------------------------------------------------------------------
__global__ void fallback_conv(const float* __restrict__ x, const float* __restrict__ kern,
                              const float* __restrict__ biases, float* __restrict__ out) {
    __shared__ float xs[1024];
    int row = blockIdx.x;
    int f = (blockIdx.y << 8) + threadIdx.x;
    int batch = row >> 13, s = row & 8191;
    const float* xb = x + (((size_t)batch << 13) << 10);
    float acc = 0.f;
    for (int tap = 0; tap < 4; tap++) {
        int ss = s - tap;
        __syncthreads();
        for (int i = threadIdx.x; i < 1024; i += 256)
            xs[i] = (ss >= 0) ? xb[((size_t)ss << 10) + i] : 0.f;
        __syncthreads();
        const float* kp = kern + ((size_t)tap << 20) + f;
        float a = 0.f;
        for (int d = 0; d < 1024; d++) a += xs[d] * kp[(size_t)d << 10];
        acc += a + biases[(tap << 10) + f];
    }
    out[((size_t)row << 10) + f] = acc;
}

extern "C" void kernel_launch(void* const* d_in, const int* in_sizes, int n_in,
                              void* d_out, int out_size, void* d_ws, size_t ws_size,
                              hipStream_t stream) {
    const float* x      = (const float*)d_in[0];
    const float* kern   = (const float*)d_in[1];
    const float* biases = (const float*)d_in[2];
    float* out = (float*)d_out;

    const size_t xbf_bytes = (size_t)4 * XBATCH * sizeof(__hip_bfloat16); // 67.1 MB
    const size_t bf_bytes  = (size_t)4096 * 1024 * sizeof(__hip_bfloat16); // 8.4 MB

    if (ws_size >= xbf_bytes + bf_bytes) {
        __hip_bfloat16* Xbf = (__hip_bfloat16*)d_ws;
        __hip_bfloat16* Bfr = (__hip_bfloat16*)((char*)d_ws + xbf_bytes);
        x_to_bf16<<<2048, 256, 0, stream>>>(x, Xbf);
        kconv_frag<<<2048, 256, 0, stream>>>(kern, Bfr);
        altconv_gemm10<<<512, 512, 0, stream>>>(Xbf, Bfr, biases, out);
    } else {
        fallback_conv<<<dim3(32768, 4), 256, 0, stream>>>(x, kern, biases, out);
    }
}

// Round 13
// 272.796 us; speedup vs baseline: 1.7749x; 1.2058x over previous
//
#include <hip/hip_runtime.h>
#include <hip/hip_bf16.h>

typedef __attribute__((ext_vector_type(4))) float f32x4;
typedef __attribute__((ext_vector_type(8))) short short8;

#define XROWS 8195            // 3 guard rows + 8192
#define XBATCH (XROWS * 1024) // elems per padded batch

__device__ __forceinline__ short f2bf(float f) {
    union { __hip_bfloat16 h; short s; } u;
    u.h = __float2bfloat16(f);
    return u.s;
}

__device__ __forceinline__ void async16(const void* g, void* l) {
    __builtin_amdgcn_global_load_lds(
        (const __attribute__((address_space(1))) unsigned int*)g,
        (__attribute__((address_space(3))) unsigned int*)l, 16, 0, 0);
}

// ---------------------------------------------------------------------------
// Prepass 1: x fp32 [4][8192][1024] -> Xbf bf16 [4][3+8192][1024], guard=0
// ---------------------------------------------------------------------------
__global__ void x_to_bf16(const float* __restrict__ x,
                          __hip_bfloat16* __restrict__ Xbf) {
    size_t idx = (size_t)blockIdx.x * blockDim.x + threadIdx.x;
    if (idx < 1536) {  // zero 4*3*1024 guard elems
        int b = (int)(idx / 384);
        int r = (int)(idx % 384);
        *reinterpret_cast<short8*>(&Xbf[(size_t)b * XBATCH + r * 8]) =
            (short8){0, 0, 0, 0, 0, 0, 0, 0};
    }
    size_t stride = (size_t)gridDim.x * blockDim.x;
    const size_t nvec = (size_t)4 * 8192 * 1024 / 8;
    for (size_t v = idx; v < nvec; v += stride) {
        size_t e = v * 8;
        int b = (int)(e >> 23);
        size_t rem = e & ((1u << 23) - 1);
        f32x4 lo = *reinterpret_cast<const f32x4*>(x + e);
        f32x4 hi = *reinterpret_cast<const f32x4*>(x + e + 4);
        short8 pk;
        pk[0] = f2bf(lo[0]); pk[1] = f2bf(lo[1]); pk[2] = f2bf(lo[2]); pk[3] = f2bf(lo[3]);
        pk[4] = f2bf(hi[0]); pk[5] = f2bf(hi[1]); pk[6] = f2bf(hi[2]); pk[7] = f2bf(hi[3]);
        *reinterpret_cast<short8*>(&Xbf[(size_t)b * XBATCH + 3 * 1024 + rem]) = pk;
    }
}

// ---------------------------------------------------------------------------
// Prepass 2: kernels [4096][1024] fp32 -> Kt [1024][4096] bf16
// ---------------------------------------------------------------------------
__global__ void kconv_transpose(const float* __restrict__ kern,
                                __hip_bfloat16* __restrict__ Kt) {
    __shared__ float tile[32][33];
    int k0 = blockIdx.x << 5;
    int f0 = blockIdx.y << 5;
    int tx = threadIdx.x & 31;
    int ty = threadIdx.x >> 5;
#pragma unroll
    for (int q = 0; q < 4; q++)
        tile[ty + q * 8][tx] = kern[(size_t)(k0 + ty + q * 8) * 1024 + f0 + tx];
    __syncthreads();
#pragma unroll
    for (int q = 0; q < 4; q++)
        Kt[((size_t)(f0 + ty + q * 8) << 12) + k0 + tx] =
            __float2bfloat16(tile[tx][ty + q * 8]);
}

// ---------------------------------------------------------------------------
// Main GEMM — R7 geometry + m201 phase body:
//   BM=BN=256, BK=64, 8 waves (2M x 4N), wave tile 128x64, 512 threads.
//   LDS 128 KiB = 2-tile dbuf x (A 32KB + B 32KB). 8 phases / 2 K-tiles.
//   Phase = {4 (+4) ds_reads -> stage half-tile -> [vmcnt(4)] -> s_barrier
//            -> 16 MFMA (setprio) -> s_barrier}.
//   ds_reads issue BEFORE the barrier (latency hides under barrier skew +
//   stragglers' MFMA tail); double barrier makes every stage provably
//   race-free (all waves consumed phase-p reads before any p+1 stage).
//   Waits: vmcnt(4) at ph4 (guards odd tile for ph5) and ph8 (guards
//   even+2 for next ph1) — counted, never 0. Stage ledger (R7-proven):
//   ph1: O.H1, ph4: E2.H0, ph5: E2.H1, ph8: O2.H0; depth 3-4 phases.
//   XOR swizzle byte^=((row&7)<<4), linear DMA dest + inverse-swizzled
//   source (rule 21) — 0 conflicts measured R3-R7.
// ---------------------------------------------------------------------------
__global__ void __launch_bounds__(512, 2)
altconv_gemm11(const __hip_bfloat16* __restrict__ Xbf,  // [4][8195][1024]
               const __hip_bfloat16* __restrict__ Kt,   // [1024][4096]
               const float* __restrict__ biases,        // [4][1024]
               float* __restrict__ out) {               // [32768][1024]
    __shared__ alignas(16) __hip_bfloat16 LS[65536];   // 128 KiB

    // bijective XCD swizzle (512 % 8 == 0); nt fastest within an XCD chunk
    int bid  = blockIdx.x;
    int tid2 = (bid & 7) * 64 + (bid >> 3);
    int mt = tid2 >> 2;           // 0..127
    int nt = tid2 & 3;            // 0..3
    int bm0   = mt << 8;
    int batch = bm0 >> 13;
    int srow0 = bm0 & 8191;
    int bn0   = nt << 8;
    const __hip_bfloat16* xb = Xbf + (size_t)batch * XBATCH;

    int t    = threadIdx.x;
    int lane = t & 63;
    int wid  = t >> 6;            // 0..7
    int wr = wid >> 2, wc = wid & 3;
    int frr = lane & 15, q = lane >> 4;
    int swz = (frr & 7) << 4;

    // fragment read elem offsets (row pitch 64 elems = 128B)
    int aRd[2][4][2], bRd[4][2];
#pragma unroll
    for (int h = 0; h < 2; h++)
#pragma unroll
        for (int m = 0; m < 4; m++) {
            int row = wr * 128 + h * 64 + m * 16 + frr;
#pragma unroll
            for (int ks = 0; ks < 2; ks++)
                aRd[h][m][ks] = row * 64 + (((ks * 64 + (q << 4)) ^ swz) >> 1);
        }
#pragma unroll
    for (int n = 0; n < 4; n++) {
        int row = wc * 64 + n * 16 + frr;
#pragma unroll
        for (int ks = 0; ks < 2; ks++)
            bRd[n][ks] = row * 64 + (((ks * 64 + (q << 4)) ^ swz) >> 1);
    }

    // staging precompute (per thread, 2 chunks per half):
    int srcA[2], dstA[2], srcB[2], dstB[2];
#pragma unroll
    for (int ld = 0; ld < 2; ld++) {
        int u  = ld * 512 + t;
        int rr = u >> 3;
        int c  = u & 7;
        int growA = (rr < 64) ? rr : rr + 64;           // HF=0 quadrant rows
        dstA[ld] = growA * 8 + c;
        srcA[ld] = growA * 1024 + ((c ^ (growA & 7)) * 8);
        dstB[ld] = rr * 8 + c;
        srcB[ld] = rr * 4096 + ((c ^ (rr & 7)) * 8);
    }

    f32x4 acc[2][4][4];
#pragma unroll
    for (int h = 0; h < 2; h++)
#pragma unroll
        for (int m = 0; m < 4; m++)
#pragma unroll
            for (int n = 0; n < 4; n++) acc[h][m][n] = (f32x4){0.f, 0.f, 0.f, 0.f};

#define STAGEH(T, HF) do {                                                    \
        int tap_ = (T) >> 4;                                                  \
        int d0_  = ((T) & 15) << 6;                                           \
        int pA_  = ((T) & 1) << 15;  /* buf elem base: 0 or 32768 */          \
        const __hip_bfloat16* xT_ =                                           \
            xb + (size_t)(srow0 + 3 - tap_) * 1024 + d0_ + (HF) * 65536;      \
        const __hip_bfloat16* bT_ =                                           \
            Kt + (((size_t)(bn0 + (HF) * 128)) << 12) + (T) * 64;             \
        _Pragma("unroll")                                                     \
        for (int ld = 0; ld < 2; ld++)                                        \
            async16(xT_ + srcA[ld], &LS[pA_ + (dstA[ld] + (HF) * 512) * 8]);  \
        _Pragma("unroll")                                                     \
        for (int ld = 0; ld < 2; ld++)                                        \
            async16(bT_ + srcB[ld],                                           \
                    &LS[pA_ + 16384 + (dstB[ld] + (HF) * 1024) * 8]);         \
    } while (0)

    short8 bfr[4];

    // m201-order phase: reads -> stage -> [wait] -> barrier -> MFMA -> barrier
#define PH(P, H, KS, RB, WAIT, STG, STGT, STGHF) do {                         \
        short8 af[4];                                                         \
        _Pragma("unroll")                                                     \
        for (int m = 0; m < 4; m++)                                           \
            af[m] = *reinterpret_cast<const short8*>(                         \
                &LS[((P) << 15) + aRd[H][m][KS]]);                            \
        if (RB) {                                                             \
            _Pragma("unroll")                                                 \
            for (int n = 0; n < 4; n++)                                       \
                bfr[n] = *reinterpret_cast<const short8*>(                    \
                    &LS[((P) << 15) + 16384 + bRd[n][KS]]);                   \
        }                                                                     \
        if (STG) STAGEH(STGT, STGHF);                                         \
        if ((WAIT) == 4) asm volatile("s_waitcnt vmcnt(4)" ::: "memory");     \
        __builtin_amdgcn_s_barrier();                                         \
        asm volatile("" ::: "memory");                                        \
        __builtin_amdgcn_s_setprio(1);                                        \
        _Pragma("unroll")                                                     \
        for (int m = 0; m < 4; m++)                                           \
            _Pragma("unroll")                                                 \
            for (int n = 0; n < 4; n++)                                       \
                acc[H][m][n] = __builtin_amdgcn_mfma_f32_16x16x32_bf16(       \
                    af[m], bfr[n], acc[H][m][n], 0, 0, 0);                    \
        __builtin_amdgcn_s_setprio(0);                                        \
        __builtin_amdgcn_s_barrier();                                         \
        asm volatile("" ::: "memory");                                        \
    } while (0)

    // prologue: T0 both halves + T1.H0 (12 loads); drain T0; barrier
    STAGEH(0, 0);
    STAGEH(0, 1);
    STAGEH(1, 0);
    asm volatile("s_waitcnt vmcnt(4)" ::: "memory");
    __builtin_amdgcn_s_barrier();
    asm volatile("" ::: "memory");

    for (int I = 0; I < 32; ++I) {
        int O  = 2 * I + 1;
        int E2 = (2 * I + 2) & 63;   // last iter wraps to dummy tile 0
        int O2 = (2 * I + 3) & 63;   // last iter wraps to dummy tile 1
        PH(0, 0, 0, 1, -1, 1, O,  1);   // ph1: stage O.H1
        PH(0, 1, 0, 0, -1, 0, 0,  0);   // ph2
        PH(0, 0, 1, 1, -1, 0, 0,  0);   // ph3
        PH(0, 1, 1, 0,  4, 1, E2, 0);   // ph4: stage E2.H0; vmcnt(4) -> O landed
        PH(1, 0, 0, 1, -1, 1, E2, 1);   // ph5: stage E2.H1
        PH(1, 1, 0, 0, -1, 0, 0,  0);   // ph6
        PH(1, 0, 1, 1, -1, 0, 0,  0);   // ph7
        PH(1, 1, 1, 0,  4, 1, O2, 0);   // ph8: stage O2.H0; vmcnt(4) -> E2 landed
    }

    // epilogue: C/D layout col=lane&15, row=(lane>>4)*4+j  [m89]
    int fr   = lane & 15;
    int rowg = (lane >> 4) << 2;
#pragma unroll
    for (int n = 0; n < 4; n++) {
        int gc = bn0 + wc * 64 + n * 16 + fr;
        float bsum = biases[gc] + biases[1024 + gc] + biases[2048 + gc] + biases[3072 + gc];
#pragma unroll
        for (int h = 0; h < 2; h++)
#pragma unroll
            for (int m = 0; m < 4; m++) {
                size_t gr = (size_t)(bm0 + wr * 128 + h * 64 + m * 16 + rowg);
#pragma unroll
                for (int j = 0; j < 4; j++) {
                    out[(gr + j) * 1024 + gc] = acc[h][m][n][j] + bsum;
                }
            }
    }
#undef STAGEH
#undef PH
}

// ---------------------------------------------------------------------------
// Fallback: plain fp32 (no workspace needed), correct but slow
// ---------------------------------------------------------------------------
__global__ void fallback_conv(const float* __restrict__ x, const float* __restrict__ kern,
                              const float* __restrict__ biases, float* __restrict__ out) {
    __shared__ float xs[1024];
    int row = blockIdx.x;
    int f = (blockIdx.y << 8) + threadIdx.x;
    int batch = row >> 13, s = row & 8191;
    const float* xb = x + (((size_t)batch << 13) << 10);
    float acc = 0.f;
    for (int tap = 0; tap < 4; tap++) {
        int ss = s - tap;
        __syncthreads();
        for (int i = threadIdx.x; i < 1024; i += 256)
            xs[i] = (ss >= 0) ? xb[((size_t)ss << 10) + i] : 0.f;
        __syncthreads();
        const float* kp = kern + ((size_t)tap << 20) + f;
        float a = 0.f;
        for (int d = 0; d < 1024; d++) a += xs[d] * kp[(size_t)d << 10];
        acc += a + biases[(tap << 10) + f];
    }
    out[((size_t)row << 10) + f] = acc;
}

extern "C" void kernel_launch(void* const* d_in, const int* in_sizes, int n_in,
                              void* d_out, int out_size, void* d_ws, size_t ws_size,
                              hipStream_t stream) {
    const float* x      = (const float*)d_in[0];
    const float* kern   = (const float*)d_in[1];
    const float* biases = (const float*)d_in[2];
    float* out = (float*)d_out;

    const size_t xbf_bytes = (size_t)4 * XBATCH * sizeof(__hip_bfloat16); // 67.1 MB
    const size_t kt_bytes  = (size_t)4096 * 1024 * sizeof(__hip_bfloat16); // 8.4 MB

    if (ws_size >= xbf_bytes + kt_bytes) {
        __hip_bfloat16* Xbf = (__hip_bfloat16*)d_ws;
        __hip_bfloat16* Kt  = (__hip_bfloat16*)((char*)d_ws + xbf_bytes);
        x_to_bf16<<<2048, 256, 0, stream>>>(x, Xbf);
        kconv_transpose<<<dim3(128, 32), 256, 0, stream>>>(kern, Kt);
        altconv_gemm11<<<512, 512, 0, stream>>>(Xbf, Kt, biases, out);
    } else {
        fallback_conv<<<dim3(32768, 4), 256, 0, stream>>>(x, kern, biases, out);
    }
}

// Round 14
// 261.170 us; speedup vs baseline: 1.8539x; 1.0445x over previous
//
#include <hip/hip_runtime.h>
#include <hip/hip_bf16.h>

typedef __attribute__((ext_vector_type(4))) float f32x4;
typedef __attribute__((ext_vector_type(8))) short short8;

#define XROWS 8195            // 3 guard rows + 8192
#define XBATCH (XROWS * 1024) // elems per padded batch

__device__ __forceinline__ short f2bf(float f) {
    union { __hip_bfloat16 h; short s; } u;
    u.h = __float2bfloat16(f);
    return u.s;
}

__device__ __forceinline__ void async16(const void* g, void* l) {
    __builtin_amdgcn_global_load_lds(
        (const __attribute__((address_space(1))) unsigned int*)g,
        (__attribute__((address_space(3))) unsigned int*)l, 16, 0, 0);
}

// ---------------------------------------------------------------------------
// Prepass 1: x fp32 [4][8192][1024] -> Xbf bf16 [4][3+8192][1024], guard=0
// ---------------------------------------------------------------------------
__global__ void x_to_bf16(const float* __restrict__ x,
                          __hip_bfloat16* __restrict__ Xbf) {
    size_t idx = (size_t)blockIdx.x * blockDim.x + threadIdx.x;
    if (idx < 1536) {  // zero 4*3*1024 guard elems
        int b = (int)(idx / 384);
        int r = (int)(idx % 384);
        *reinterpret_cast<short8*>(&Xbf[(size_t)b * XBATCH + r * 8]) =
            (short8){0, 0, 0, 0, 0, 0, 0, 0};
    }
    size_t stride = (size_t)gridDim.x * blockDim.x;
    const size_t nvec = (size_t)4 * 8192 * 1024 / 8;
    for (size_t v = idx; v < nvec; v += stride) {
        size_t e = v * 8;
        int b = (int)(e >> 23);
        size_t rem = e & ((1u << 23) - 1);
        f32x4 lo = *reinterpret_cast<const f32x4*>(x + e);
        f32x4 hi = *reinterpret_cast<const f32x4*>(x + e + 4);
        short8 pk;
        pk[0] = f2bf(lo[0]); pk[1] = f2bf(lo[1]); pk[2] = f2bf(lo[2]); pk[3] = f2bf(lo[3]);
        pk[4] = f2bf(hi[0]); pk[5] = f2bf(hi[1]); pk[6] = f2bf(hi[2]); pk[7] = f2bf(hi[3]);
        *reinterpret_cast<short8*>(&Xbf[(size_t)b * XBATCH + 3 * 1024 + rem]) = pk;
    }
}

// ---------------------------------------------------------------------------
// Prepass 2: kernels [4096][1024] fp32 -> Kt [1024][4096] bf16
// ---------------------------------------------------------------------------
__global__ void kconv_transpose(const float* __restrict__ kern,
                                __hip_bfloat16* __restrict__ Kt) {
    __shared__ float tile[32][33];
    int k0 = blockIdx.x << 5;
    int f0 = blockIdx.y << 5;
    int tx = threadIdx.x & 31;
    int ty = threadIdx.x >> 5;
#pragma unroll
    for (int q = 0; q < 4; q++)
        tile[ty + q * 8][tx] = kern[(size_t)(k0 + ty + q * 8) * 1024 + f0 + tx];
    __syncthreads();
#pragma unroll
    for (int q = 0; q < 4; q++)
        Kt[((size_t)(f0 + ty + q * 8) << 12) + k0 + tx] =
            __float2bfloat16(tile[tx][ty + q * 8]);
}

// ---------------------------------------------------------------------------
// Main GEMM — R7 structure (best measured: 234us GEMM), setprio removed
//   (m190: setprio is slightly negative on barrier-lockstep structures).
//   BM=BN=256, BK=64, 8 waves (2M x 4N), wave tile 128x64, 512 threads.
//   LDS 128 KiB = 2-tile dbuf x (A 32KB + B 32KB). 8 phases / 2 K-tiles;
//   phase = one C-quadrant (h,ks): 4 A ds_reads (+4 B on ks-change),
//   1 half-tile stage (4 async16), 1 barrier, 16 MFMA. Counted vmcnt(4)
//   at phases 1 & 5 only (1 half-tile in flight; >=3-phase cover).
//   XOR swizzle byte^=((row&7)<<4) -> 0 bank conflicts (measured R3-R13);
//   linear DMA dest + inverse-swizzled source (rule 21). Stage halves
//   match quadrant row sets so every LDS region is overwritten >=1
//   barrier after its last read.
// ---------------------------------------------------------------------------
__global__ void __launch_bounds__(512, 2)
altconv_gemm12(const __hip_bfloat16* __restrict__ Xbf,  // [4][8195][1024]
               const __hip_bfloat16* __restrict__ Kt,   // [1024][4096]
               const float* __restrict__ biases,        // [4][1024]
               float* __restrict__ out) {               // [32768][1024]
    __shared__ alignas(16) __hip_bfloat16 LS[65536];   // 128 KiB

    // bijective XCD swizzle (512 % 8 == 0); nt fastest within an XCD chunk
    int bid  = blockIdx.x;
    int tid2 = (bid & 7) * 64 + (bid >> 3);
    int mt = tid2 >> 2;           // 0..127
    int nt = tid2 & 3;            // 0..3
    int bm0   = mt << 8;
    int batch = bm0 >> 13;
    int srow0 = bm0 & 8191;
    int bn0   = nt << 8;
    const __hip_bfloat16* xb = Xbf + (size_t)batch * XBATCH;

    int t    = threadIdx.x;
    int lane = t & 63;
    int wid  = t >> 6;            // 0..7
    int wr = wid >> 2, wc = wid & 3;
    int frr = lane & 15, q = lane >> 4;
    int swz = (frr & 7) << 4;

    // fragment read elem offsets (row pitch 64 elems = 128B)
    int aRd[2][4][2], bRd[4][2];
#pragma unroll
    for (int h = 0; h < 2; h++)
#pragma unroll
        for (int m = 0; m < 4; m++) {
            int row = wr * 128 + h * 64 + m * 16 + frr;
#pragma unroll
            for (int ks = 0; ks < 2; ks++)
                aRd[h][m][ks] = row * 64 + (((ks * 64 + (q << 4)) ^ swz) >> 1);
        }
#pragma unroll
    for (int n = 0; n < 4; n++) {
        int row = wc * 64 + n * 16 + frr;
#pragma unroll
        for (int ks = 0; ks < 2; ks++)
            bRd[n][ks] = row * 64 + (((ks * 64 + (q << 4)) ^ swz) >> 1);
    }

    // staging precompute (per thread, 2 chunks per half):
    int srcA[2], dstA[2], srcB[2], dstB[2];
#pragma unroll
    for (int ld = 0; ld < 2; ld++) {
        int u  = ld * 512 + t;
        int rr = u >> 3;
        int c  = u & 7;
        int growA = (rr < 64) ? rr : rr + 64;           // HF=0 quadrant rows
        dstA[ld] = growA * 8 + c;
        srcA[ld] = growA * 1024 + ((c ^ (growA & 7)) * 8);
        dstB[ld] = rr * 8 + c;
        srcB[ld] = rr * 4096 + ((c ^ (rr & 7)) * 8);
    }

    f32x4 acc[2][4][4];
#pragma unroll
    for (int h = 0; h < 2; h++)
#pragma unroll
        for (int m = 0; m < 4; m++)
#pragma unroll
            for (int n = 0; n < 4; n++) acc[h][m][n] = (f32x4){0.f, 0.f, 0.f, 0.f};

#define STAGEH(T, HF) do {                                                    \
        int tap_ = (T) >> 4;                                                  \
        int d0_  = ((T) & 15) << 6;                                           \
        int pA_  = ((T) & 1) << 15;  /* buf elem base: 0 or 32768 */          \
        const __hip_bfloat16* xT_ =                                           \
            xb + (size_t)(srow0 + 3 - tap_) * 1024 + d0_ + (HF) * 65536;      \
        const __hip_bfloat16* bT_ =                                           \
            Kt + (((size_t)(bn0 + (HF) * 128)) << 12) + (T) * 64;             \
        _Pragma("unroll")                                                     \
        for (int ld = 0; ld < 2; ld++)                                        \
            async16(xT_ + srcA[ld], &LS[pA_ + (dstA[ld] + (HF) * 512) * 8]);  \
        _Pragma("unroll")                                                     \
        for (int ld = 0; ld < 2; ld++)                                        \
            async16(bT_ + srcB[ld],                                           \
                    &LS[pA_ + 16384 + (dstB[ld] + (HF) * 1024) * 8]);         \
    } while (0)

    short8 bfr[4];

    // R7-order phase: [wait] -> barrier -> reads -> stage -> 16 MFMA
#define PH(P, H, KS, RB, WAIT, STG, STGT, STGHF) do {                         \
        if ((WAIT) == 4) asm volatile("s_waitcnt vmcnt(4)" ::: "memory");     \
        else if ((WAIT) == 0) asm volatile("s_waitcnt vmcnt(0)" ::: "memory");\
        __builtin_amdgcn_s_barrier();                                         \
        asm volatile("" ::: "memory");                                        \
        short8 af[4];                                                         \
        _Pragma("unroll")                                                     \
        for (int m = 0; m < 4; m++)                                           \
            af[m] = *reinterpret_cast<const short8*>(                         \
                &LS[((P) << 15) + aRd[H][m][KS]]);                            \
        if (RB) {                                                             \
            _Pragma("unroll")                                                 \
            for (int n = 0; n < 4; n++)                                       \
                bfr[n] = *reinterpret_cast<const short8*>(                    \
                    &LS[((P) << 15) + 16384 + bRd[n][KS]]);                   \
        }                                                                     \
        if (STG) STAGEH(STGT, STGHF);                                         \
        _Pragma("unroll")                                                     \
        for (int m = 0; m < 4; m++)                                           \
            _Pragma("unroll")                                                 \
            for (int n = 0; n < 4; n++)                                       \
                acc[H][m][n] = __builtin_amdgcn_mfma_f32_16x16x32_bf16(       \
                    af[m], bfr[n], acc[H][m][n], 0, 0, 0);                    \
    } while (0)

    // prologue: T0 both halves, T1 half0 (12 loads in flight)
    STAGEH(0, 0);
    STAGEH(0, 1);
    STAGEH(1, 0);

    for (int I = 0; I < 31; ++I) {
        int T1 = 2 * I + 1, T2 = 2 * I + 2, T3 = 2 * I + 3;
        PH(0, 0, 0, 1, 4, 1, T1, 1);   // wait T0-class done; stage odd.HF1
        PH(0, 1, 0, 0, -1, 0, 0, 0);
        PH(0, 0, 1, 1, -1, 0, 0, 0);
        PH(0, 1, 1, 0, -1, 1, T2, 0);  // even+2 half0 (rows free after ph3)
        PH(1, 0, 0, 1, 4, 1, T2, 1);   // wait odd done; even+2 half1
        PH(1, 1, 0, 0, -1, 0, 0, 0);
        PH(1, 0, 1, 1, -1, 0, 0, 0);
        PH(1, 1, 1, 0, -1, 1, T3, 0);  // odd+2 half0
    }
    // epilogue super: tiles 62 (buf0), 63 (buf1); finish 63.HF1, then drain
    PH(0, 0, 0, 1, 4, 1, 63, 1);
    PH(0, 1, 0, 0, -1, 0, 0, 0);
    PH(0, 0, 1, 1, -1, 0, 0, 0);
    PH(0, 1, 1, 0, -1, 0, 0, 0);
    PH(1, 0, 0, 1, 0, 0, 0, 0);        // vmcnt(0): tile 63 fully landed
    PH(1, 1, 0, 0, -1, 0, 0, 0);
    PH(1, 0, 1, 1, -1, 0, 0, 0);
    PH(1, 1, 1, 0, -1, 0, 0, 0);

    // epilogue: C/D layout col=lane&15, row=(lane>>4)*4+j  [m89]
    int fr   = lane & 15;
    int rowg = (lane >> 4) << 2;
#pragma unroll
    for (int n = 0; n < 4; n++) {
        int gc = bn0 + wc * 64 + n * 16 + fr;
        float bsum = biases[gc] + biases[1024 + gc] + biases[2048 + gc] + biases[3072 + gc];
#pragma unroll
        for (int h = 0; h < 2; h++)
#pragma unroll
            for (int m = 0; m < 4; m++) {
                size_t gr = (size_t)(bm0 + wr * 128 + h * 64 + m * 16 + rowg);
#pragma unroll
                for (int j = 0; j < 4; j++) {
                    out[(gr + j) * 1024 + gc] = acc[h][m][n][j] + bsum;
                }
            }
    }
#undef STAGEH
#undef PH
}

// ---------------------------------------------------------------------------
// Fallback: plain fp32 (no workspace needed), correct but slow
// ---------------------------------------------------------------------------
__global__ void fallback_conv(const float* __restrict__ x, const float* __restrict__ kern,
                              const float* __restrict__ biases, float* __restrict__ out) {
    __shared__ float xs[1024];
    int row = blockIdx.x;
    int f = (blockIdx.y << 8) + threadIdx.x;
    int batch = row >> 13, s = row & 8191;
    const float* xb = x + (((size_t)batch << 13) << 10);
    float acc = 0.f;
    for (int tap = 0; tap < 4; tap++) {
        int ss = s - tap;
        __syncthreads();
        for (int i = threadIdx.x; i < 1024; i += 256)
            xs[i] = (ss >= 0) ? xb[((size_t)ss << 10) + i] : 0.f;
        __syncthreads();
        const float* kp = kern + ((size_t)tap << 20) + f;
        float a = 0.f;
        for (int d = 0; d < 1024; d++) a += xs[d] * kp[(size_t)d << 10];
        acc += a + biases[(tap << 10) + f];
    }
    out[((size_t)row << 10) + f] = acc;
}

extern "C" void kernel_launch(void* const* d_in, const int* in_sizes, int n_in,
                              void* d_out, int out_size, void* d_ws, size_t ws_size,
                              hipStream_t stream) {
    const float* x      = (const float*)d_in[0];
    const float* kern   = (const float*)d_in[1];
    const float* biases = (const float*)d_in[2];
    float* out = (float*)d_out;

    const size_t xbf_bytes = (size_t)4 * XBATCH * sizeof(__hip_bfloat16); // 67.1 MB
    const size_t kt_bytes  = (size_t)4096 * 1024 * sizeof(__hip_bfloat16); // 8.4 MB

    if (ws_size >= xbf_bytes + kt_bytes) {
        __hip_bfloat16* Xbf = (__hip_bfloat16*)d_ws;
        __hip_bfloat16* Kt  = (__hip_bfloat16*)((char*)d_ws + xbf_bytes);
        x_to_bf16<<<2048, 256, 0, stream>>>(x, Xbf);
        kconv_transpose<<<dim3(128, 32), 256, 0, stream>>>(kern, Kt);
        altconv_gemm12<<<512, 512, 0, stream>>>(Xbf, Kt, biases, out);
    } else {
        fallback_conv<<<dim3(32768, 4), 256, 0, stream>>>(x, kern, biases, out);
    }
}